// Round 3
// baseline (628.887 us; speedup 1.0000x reference)
//
#include <hip/hip_runtime.h>
#include <hip/hip_cooperative_groups.h>

namespace cg = cooperative_groups;

// Problem constants
#define NROWS 8192
#define INF   4096
#define OUTF  4096
#define G     1024          // INF / 4

typedef _Float16 f16x8 __attribute__((ext_vector_type(8)));
typedef float    f32x4 __attribute__((ext_vector_type(4)));

// ws layout:
//   [0..16)                  float scales[3]: [0]=act_scale, [2]=act_scale*0.25*wscale
//   [16 .. 16+4096)          1024 float block-partial maxes
//   [8208 ..)                x_sum f16 [NROWS][G]   (16 MB)
//   [8208 + NROWS*G*2 ..)    w_sum f16 [OUTF][G]    (8 MB)

// ---------- Kernel 1 (cooperative): absmax + w-sum | grid.sync | quantize ----------
// Hypothesis under test: each kernel launch in this pipeline costs ~115 µs despite
// ~30 µs of roofline work; fusing all prep into one cooperative kernel removes two
// launch/drain boundaries. 1024 blocks x 256 thr -> guaranteed co-resident even at
// 128 VGPRs (4 blocks/CU x 256 CUs).
__global__ __launch_bounds__(256, 4) void prep(
    const float4* __restrict__ x,
    const float4* __restrict__ w,
    const float* __restrict__ wscale,
    float* __restrict__ partial,
    float* __restrict__ sc,
    _Float16* __restrict__ xs,
    _Float16* __restrict__ ws) {

    const int t = threadIdx.x;
    const int b = blockIdx.x;
    const int tid = b * 256 + t;
    const int stride = 1024 * 256;
    const int lane = t & 63, wave = t >> 6;
    __shared__ float wm[4];

    // ---- Phase A1: absmax partials over x (8388608 f4 / 262144 thr = 32 each)
    {
        float m = 0.f;
        int i = tid;
        #pragma unroll 4
        for (int it = 0; it < 32; ++it, i += stride) {
            float4 v = x[i];
            m = fmaxf(m, fmaxf(fmaxf(fabsf(v.x), fabsf(v.y)),
                               fmaxf(fabsf(v.z), fabsf(v.w))));
        }
        for (int off = 32; off; off >>= 1)
            m = fmaxf(m, __shfl_down(m, off));
        if (lane == 0) wm[wave] = m;
        __syncthreads();
        if (t == 0)
            partial[b] = fmaxf(fmaxf(wm[0], wm[1]), fmaxf(wm[2], wm[3]));
    }
    // ---- Phase A2: w group sums (4194304 f4 = 16 each). NT loads: w never re-read;
    // keep x L3-resident for phase B.
    {
        int i = tid;
        #pragma unroll 4
        for (int it = 0; it < 16; ++it, i += stride) {
            f32x4 v = __builtin_nontemporal_load((const f32x4*)&w[i]);
            ws[i] = (_Float16)(v.x + v.y + v.z + v.w);  // integer in [-4,4]: exact
        }
    }
    __threadfence();
    cg::this_grid().sync();

    // ---- Phase B: every block re-reduces the 1024 partials, then quantizes x.
    {
        float m = fmaxf(fmaxf(partial[t], partial[t + 256]),
                        fmaxf(partial[t + 512], partial[t + 768]));
        for (int off = 32; off; off >>= 1)
            m = fmaxf(m, __shfl_down(m, off));
        if (lane == 0) wm[wave] = m;
        __syncthreads();
        const float bm = fmaxf(fmaxf(wm[0], wm[1]), fmaxf(wm[2], wm[3]));
        const float inv = 127.0f / bm;
        if (b == 0 && t == 0) {
            float s = bm * (1.0f / 127.0f);
            sc[0] = s;                       // act_scale
            sc[2] = s * 0.25f * wscale[0];   // fused epilogue scale for GEMM
        }
        // No clamps: |v|*127/bm <= 127*(1+eps) < 127.5, rint exact.
        int i = tid;
        #pragma unroll 4
        for (int it = 0; it < 32; ++it, i += stride) {
            float4 v = x[i];
            xs[i] = (_Float16)(rintf(v.x * inv) + rintf(v.y * inv) +
                               rintf(v.z * inv) + rintf(v.w * inv));
        }
    }
}

// ---------- Kernel 2: f16 MFMA GEMM, 256x256 tile, BK=64, 8 waves, dbuf ----------
#define BM 256
#define BN 256
#define BK 64
#define KSTEPS (G / BK)   // 16

__device__ __forceinline__ void async_copy16(const void* g, void* l) {
    __builtin_amdgcn_global_load_lds(
        (const __attribute__((address_space(1))) unsigned int*)g,
        (__attribute__((address_space(3))) unsigned int*)l,
        16, 0, 0);
}

__global__ __launch_bounds__(512, 2) void gemm_kernel(
    const _Float16* __restrict__ A,   // x_sum [8192][1024]
    const _Float16* __restrict__ B,   // w_sum [4096][1024]
    const float* __restrict__ bias,
    const float* __restrict__ sc,
    float* __restrict__ out) {

    // Double-buffered 2 x (32 KB A + 32 KB B) = 128 KB. 1 block/CU (VGPR-bound
    // at 2 waves/SIMD anyway). Staged bytes/MAC drop 1.5x vs 256x128xBK32.
    __shared__ alignas(16) _Float16 As[2][BM * BK];
    __shared__ alignas(16) _Float16 Bs[2][BN * BK];

    const int t = threadIdx.x;
    const int lane = t & 63;
    const int wave = t >> 6;            // 0..7
    const int wm = (wave >> 2) * 128;   // 2 wave-rows (M)
    const int wn = (wave & 3) * 64;     // 4 wave-cols (N)

    const long rowA0 = (long)blockIdx.y * BM;
    const long rowB0 = (long)blockIdx.x * BN;

    f32x4 acc[8][4] = {};

    // Staging: chunk = 8 rows x 128 B = 1 KB. global_load_lds writes linear LDS
    // (chunk_base + lane*16); the bank-conflict swizzle
    //   LDS[row][cb] = G[row][cb ^ ((row&7)<<4)]
    // is realized by inverse-swizzling the GLOBAL source column (rule #21):
    // lane l: row = l>>3, src col-byte = ((l&7) ^ (l>>3)) << 4.
    const int srow = lane >> 3;
    const int scolB = ((lane & 7) ^ srow) << 4;

    auto stage = [&](int buf, int kt) {
        const long kbyte = (long)kt * (BK * 2);
        #pragma unroll
        for (int i = 0; i < 8; ++i) {
            const int c = wave * 8 + i;            // 64 chunks: 0-31 A, 32-63 B
            if (c < 32) {
                const long row = c * 8 + srow;
                async_copy16((const char*)A + (rowA0 + row) * (G * 2) + kbyte + scolB,
                             (char*)&As[buf][0] + c * 1024);
            } else {
                const long row = (c - 32) * 8 + srow;
                async_copy16((const char*)B + (rowB0 + row) * (G * 2) + kbyte + scolB,
                             (char*)&Bs[buf][0] + (c - 32) * 1024);
            }
        }
    };

    // Read-side: phys byte-in-row = (kh*64 + (lane>>4)*16) ^ ((row&7)<<4),
    // row&7 == lane&7 for fragment rows. 8 rows fill all 32 banks -> 2-way (free).
    const int fr = lane & 15;
    const int fq16 = (lane >> 4) << 4;
    const int fswz = (lane & 7) << 4;

    stage(0, 0);
    int buf = 0;
    for (int ks = 0; ks < KSTEPS; ++ks) {
        if (ks + 1 < KSTEPS) {
            stage(buf ^ 1, ks + 1);   // 8 loads/thread into the other buffer
            // FIFO drain: oldest 8 = tile ks; keep tile ks+1's 8 in flight.
            asm volatile("s_waitcnt vmcnt(8)" ::: "memory");
        } else {
            asm volatile("s_waitcnt vmcnt(0)" ::: "memory");
        }
        __builtin_amdgcn_s_barrier();   // all waves' tile-ks stages landed

        #pragma unroll
        for (int kh = 0; kh < 2; ++kh) {
            const int cb = kh * 64;
            f16x8 af[8], bf[4];
            #pragma unroll
            for (int mi = 0; mi < 8; ++mi)
                af[mi] = *(const f16x8*)((const char*)&As[buf][0]
                           + (wm + mi * 16 + fr) * 128 + ((cb + fq16) ^ fswz));
            #pragma unroll
            for (int nj = 0; nj < 4; ++nj)
                bf[nj] = *(const f16x8*)((const char*)&Bs[buf][0]
                           + (wn + nj * 16 + fr) * 128 + ((cb + fq16) ^ fswz));
            #pragma unroll
            for (int mi = 0; mi < 8; ++mi)
                #pragma unroll
                for (int nj = 0; nj < 4; ++nj)
                    acc[mi][nj] = __builtin_amdgcn_mfma_f32_16x16x32_f16(
                        af[mi], bf[nj], acc[mi][nj], 0, 0, 0);
        }

        __builtin_amdgcn_s_barrier();   // reads of buf done before it is restaged
        buf ^= 1;
    }

    // Epilogue: D[m=(lane>>4)*4+r][n=lane&15] per 16x16 tile. Plain stores
    // (round-1/2 A/B: NT stores raised FETCH, no win).
    const float scale = sc[2];
    const int r0 = (int)rowA0 + wm + (lane >> 4) * 4;
    const int c0 = (int)rowB0 + wn + fr;
    #pragma unroll
    for (int nj = 0; nj < 4; ++nj) {
        const int col = c0 + nj * 16;
        const float b = bias[col];
        #pragma unroll
        for (int mi = 0; mi < 8; ++mi) {
            const int row = r0 + mi * 16;
            #pragma unroll
            for (int r = 0; r < 4; ++r)
                out[(long)(row + r) * OUTF + col] = acc[mi][nj][r] * scale + b;
        }
    }
}

extern "C" void kernel_launch(void* const* d_in, const int* in_sizes, int n_in,
                              void* d_out, int out_size, void* d_ws, size_t ws_size,
                              hipStream_t stream) {
    const float4* input  = (const float4*)d_in[0];   // [8192][4096]
    const float4* weight = (const float4*)d_in[1];   // [4096][4096]
    const float* wscale  = (const float*)d_in[2];    // [1]
    const float* bias    = (const float*)d_in[3];    // [4096]
    float* out = (float*)d_out;

    float* scales   = (float*)d_ws;
    float* partials = (float*)((char*)d_ws + 16);
    _Float16* x_sum = (_Float16*)((char*)d_ws + 8208);
    _Float16* w_sum = (_Float16*)((char*)d_ws + 8208 + (size_t)NROWS * G * 2);

    void* args[] = {(void*)&input, (void*)&weight, (void*)&wscale, (void*)&partials,
                    (void*)&scales, (void*)&x_sum, (void*)&w_sum};
    hipLaunchCooperativeKernel((void*)prep, dim3(1024), dim3(256), args, 0, stream);

    gemm_kernel<<<dim3(OUTF / BN, NROWS / BM), 512, 0, stream>>>(
        x_sum, w_sum, bias, scales, out);
}

// Round 6
// 389.678 us; speedup vs baseline: 1.6139x; 1.6139x over previous
//
#include <hip/hip_runtime.h>

// Problem constants
#define NROWS 8192
#define INF   4096
#define OUTF  4096
#define G     1024          // INF / 4

typedef _Float16 f16x8 __attribute__((ext_vector_type(8)));
typedef float    f32x4 __attribute__((ext_vector_type(4)));

// ws layout:
//   [0..16)                  float scales[3]: [0]=act_scale, [2]=act_scale*0.25*wscale
//   [16 .. 16+8192)          2048 float block-partial maxes
//   [8208 ..)                x_sum f16 [NROWS][G]   (16 MB)
//   [8208 + NROWS*G*2 ..)    w_sum f16 [OUTF][G]    (8 MB)

// ---------- Kernel 1: absmax partials over x ----------
// MLP-first design: 8 independent 16B loads in flight per lane (round-3 counters
// showed prep at 588 GB/s, VALUBusy 2.3% -> latency-bound with ~2 loads/CU in
// flight; this gives ~100 KB/CU in flight). Block owns a contiguous 64 KB chunk.
// 2048 blocks x 256 threads x 16 float4 = 8388608 float4 = all of x.
__global__ void absmax_part(const float4* __restrict__ x,
                            float* __restrict__ partial) {
    const int t = threadIdx.x;
    const long base = (long)blockIdx.x * 4096 + t;
    float m[8] = {0.f, 0.f, 0.f, 0.f, 0.f, 0.f, 0.f, 0.f};
    #pragma unroll
    for (int batch = 0; batch < 2; ++batch) {
        float4 v[8];
        #pragma unroll
        for (int k = 0; k < 8; ++k)
            v[k] = x[base + batch * 2048 + k * 256];
        #pragma unroll
        for (int k = 0; k < 8; ++k)
            m[k] = fmaxf(m[k], fmaxf(fmaxf(fabsf(v[k].x), fabsf(v[k].y)),
                                     fmaxf(fabsf(v[k].z), fabsf(v[k].w))));
    }
    float mm = 0.f;
    #pragma unroll
    for (int k = 0; k < 8; ++k) mm = fmaxf(mm, m[k]);
    for (int off = 32; off; off >>= 1)
        mm = fmaxf(mm, __shfl_down(mm, off));
    __shared__ float wm[4];
    const int lane = t & 63, wave = t >> 6;
    if (lane == 0) wm[wave] = mm;
    __syncthreads();
    if (t == 0)
        partial[blockIdx.x] = fmaxf(fmaxf(wm[0], wm[1]), fmaxf(wm[2], wm[3]));
}

// ---------- Kernel 2: w group-sums ----------
// Lane owns 8 CONSECUTIVE groups: 8x16B loads (128 B contiguous per lane, all in
// flight) -> one packed 16 B store of 8 f16.
// 2048 blocks x 256 x 8 = 4194304 groups = all of w.
__global__ void wsum_kernel(const float* __restrict__ w,
                            _Float16* __restrict__ ws) {
    const long g0 = (long)blockIdx.x * 2048 + (long)threadIdx.x * 8;
    f32x4 v[8];
    #pragma unroll
    for (int j = 0; j < 8; ++j)
        v[j] = *(const f32x4*)(w + (g0 + j) * 4);
    f16x8 r;
    #pragma unroll
    for (int j = 0; j < 8; ++j)
        r[j] = (_Float16)(v[j][0] + v[j][1] + v[j][2] + v[j][3]);  // int in [-4,4]: exact
    *(f16x8*)(ws + g0) = r;
}

// ---------- Kernel 3: reduce partials in-block + quantize + group-sum x ----------
// Every block re-reduces the 2048 partials (deterministic; 8 KB L2-hit read).
// Lane owns 8 consecutive groups -> 8x16B loads in flight + one 16B packed store.
// No clamps: |v|*127/bm <= 127*(1+eps) < 127.5, rint exact.
// 4096 blocks x 256 x 8 = 8388608 groups = all of x.
__global__ void xquant(const float* __restrict__ x,
                       const float* __restrict__ partial,
                       const float* __restrict__ wscale,
                       float* __restrict__ sc,
                       _Float16* __restrict__ xs) {
    const int t = threadIdx.x;
    float m = 0.f;
    #pragma unroll
    for (int u = 0; u < 8; ++u)
        m = fmaxf(m, partial[t + u * 256]);
    for (int off = 32; off; off >>= 1)
        m = fmaxf(m, __shfl_down(m, off));
    __shared__ float wm[4];
    const int lane = t & 63, wave = t >> 6;
    if (lane == 0) wm[wave] = m;
    __syncthreads();
    const float bm = fmaxf(fmaxf(wm[0], wm[1]), fmaxf(wm[2], wm[3]));
    const float inv = 127.0f / bm;
    if (blockIdx.x == 0 && t == 0) {
        float s = bm * (1.0f / 127.0f);
        sc[0] = s;                       // act_scale
        sc[2] = s * 0.25f * wscale[0];   // fused epilogue scale for GEMM
    }
    const long g0 = (long)blockIdx.x * 2048 + (long)t * 8;
    f32x4 v[8];
    #pragma unroll
    for (int j = 0; j < 8; ++j)
        v[j] = *(const f32x4*)(x + (g0 + j) * 4);
    f16x8 r;
    #pragma unroll
    for (int j = 0; j < 8; ++j)
        r[j] = (_Float16)(rintf(v[j][0] * inv) + rintf(v[j][1] * inv) +
                          rintf(v[j][2] * inv) + rintf(v[j][3] * inv));
    *(f16x8*)(xs + g0) = r;
}

// ---------- Kernel 4: f16 MFMA GEMM (round-1 config: best measured, 112-114 us) ----------
#define BM 256
#define BN 128
#define BK 32

__device__ __forceinline__ void async_copy16(const void* g, void* l) {
    __builtin_amdgcn_global_load_lds(
        (const __attribute__((address_space(1))) unsigned int*)g,
        (__attribute__((address_space(3))) unsigned int*)l,
        16, 0, 0);
}

__global__ __launch_bounds__(256, 2) void gemm_kernel(
    const _Float16* __restrict__ A,
    const _Float16* __restrict__ B,
    const float* __restrict__ bias,
    const float* __restrict__ sc,
    float* __restrict__ out) {

    // Double-buffered: 2 x (16 KB A + 8 KB B) = 48 KB -> 2 blocks/CU.
    __shared__ alignas(16) _Float16 As[2][BM * BK];
    __shared__ alignas(16) _Float16 Bs[2][BN * BK];

    const int t = threadIdx.x;
    const int lane = t & 63;
    const int wave = t >> 6;
    const int wm = (wave >> 1) * 128;   // wave tile: 128 rows x 64 cols
    const int wn = (wave & 1) * 64;

    const long rowA0 = (long)blockIdx.y * BM;
    const long rowB0 = (long)blockIdx.x * BN;

    f32x4 acc[8][4] = {};

    // Staging: chunk = 1 KB = 16 rows x 32 f16. LDS dest linear (global_load_lds
    // writes base + lane*16); bank-conflict swizzle applied on the GLOBAL source
    // column (both-sides rule): phys_col8 = col8 ^ ((row>>1)&3)<<3.
    const int srow = lane >> 2;
    const int scol = ((lane & 3) << 3) ^ (((lane >> 3) & 3) << 3);
    const int swzR = ((lane >> 1) & 3) << 3;

    auto stage = [&](int buf, int k0) {
        #pragma unroll
        for (int i = 0; i < 6; ++i) {
            const int c = wave * 6 + i;       // wave-uniform chunk id, 24 = 16 A + 8 B
            if (c < 16) {
                const int row = c * 16 + srow;
                async_copy16(A + (rowA0 + row) * (long)G + k0 + scol, &As[buf][c * 512]);
            } else {
                const int row = (c - 16) * 16 + srow;
                async_copy16(B + (rowB0 + row) * (long)G + k0 + scol, &Bs[buf][(c - 16) * 512]);
            }
        }
    };

    stage(0, 0);
    __syncthreads();   // compiler drains vmcnt(0) before s_barrier

    int cur = 0;
    for (int ks = 0; ks < G / BK; ++ks) {
        if (ks + 1 < G / BK) stage(cur ^ 1, (ks + 1) * BK);

        f16x8 af[8], bf[4];
        #pragma unroll
        for (int mi = 0; mi < 8; ++mi)
            af[mi] = *(const f16x8*)&As[cur][(wm + mi * 16 + (lane & 15)) * BK
                                            + (((lane >> 4) * 8) ^ swzR)];
        #pragma unroll
        for (int nj = 0; nj < 4; ++nj)
            bf[nj] = *(const f16x8*)&Bs[cur][(wn + nj * 16 + (lane & 15)) * BK
                                            + (((lane >> 4) * 8) ^ swzR)];

        #pragma unroll
        for (int mi = 0; mi < 8; ++mi)
            #pragma unroll
            for (int nj = 0; nj < 4; ++nj)
                acc[mi][nj] = __builtin_amdgcn_mfma_f32_16x16x32_f16(
                    af[mi], bf[nj], acc[mi][nj], 0, 0, 0);

        __syncthreads();  // reads of buf[cur] done + stages into buf[cur^1] drained
        cur ^= 1;
    }

    // epilogue: D[m=(lane>>4)*4+r][n=lane&15] per 16x16 tile
    const float scale = sc[2];
    const int r0 = (int)rowA0 + wm + (lane >> 4) * 4;
    const int c0 = (int)rowB0 + wn + (lane & 15);
    #pragma unroll
    for (int nj = 0; nj < 4; ++nj) {
        const int col = c0 + nj * 16;
        const float b = bias[col];
        #pragma unroll
        for (int mi = 0; mi < 8; ++mi) {
            const int row = r0 + mi * 16;
            #pragma unroll
            for (int r = 0; r < 4; ++r)
                out[(long)(row + r) * OUTF + col] = acc[mi][nj][r] * scale + b;
        }
    }
}

extern "C" void kernel_launch(void* const* d_in, const int* in_sizes, int n_in,
                              void* d_out, int out_size, void* d_ws, size_t ws_size,
                              hipStream_t stream) {
    const float* input  = (const float*)d_in[0];   // [8192][4096]
    const float* weight = (const float*)d_in[1];   // [4096][4096]
    const float* wscale = (const float*)d_in[2];   // [1]
    const float* bias   = (const float*)d_in[3];   // [4096]
    float* out = (float*)d_out;

    float* scales   = (float*)d_ws;
    float* partials = (float*)((char*)d_ws + 16);
    _Float16* x_sum = (_Float16*)((char*)d_ws + 8208);
    _Float16* w_sum = (_Float16*)((char*)d_ws + 8208 + (size_t)NROWS * G * 2);

    absmax_part<<<2048, 256, 0, stream>>>((const float4*)input, partials);
    wsum_kernel<<<2048, 256, 0, stream>>>(weight, w_sum);
    xquant<<<4096, 256, 0, stream>>>(input, partials, wscale, scales, x_sum);
    gemm_kernel<<<dim3(OUTF / BN, NROWS / BM), 256, 0, stream>>>(
        x_sum, w_sum, bias, scales, out);
}

// Round 7
// 383.330 us; speedup vs baseline: 1.6406x; 1.0166x over previous
//
#include <hip/hip_runtime.h>

// Problem constants
#define NROWS 8192
#define INF   4096
#define OUTF  4096
#define G     1024          // INF / 4

typedef _Float16 f16x8 __attribute__((ext_vector_type(8)));
typedef float    f32x4 __attribute__((ext_vector_type(4)));

// ws layout:
//   [0..16)                  float scales[3]: [0]=act_scale, [2]=act_scale*0.25*wscale
//   [16 .. 16+8192)          2048 float block-partial maxes
//   [8208 ..)                x_sum f16 [NROWS][G]   (16 MB)
//   [8208 + NROWS*G*2 ..)    w_sum f16 [OUTF][G]    (8 MB)

// ---------- Kernel 1: absmax partials over x ----------
// 2048 blocks x 256 threads x 16 float4 = 8388608 float4 = all of x.
// (r6 A/B result: prep time is structure-invariant; keep the simple proven form.)
__global__ void absmax_part(const float4* __restrict__ x,
                            float* __restrict__ partial) {
    const int t = threadIdx.x;
    const long base = (long)blockIdx.x * 4096 + t;
    float m[8] = {0.f, 0.f, 0.f, 0.f, 0.f, 0.f, 0.f, 0.f};
    #pragma unroll
    for (int batch = 0; batch < 2; ++batch) {
        float4 v[8];
        #pragma unroll
        for (int k = 0; k < 8; ++k)
            v[k] = x[base + batch * 2048 + k * 256];
        #pragma unroll
        for (int k = 0; k < 8; ++k)
            m[k] = fmaxf(m[k], fmaxf(fmaxf(fabsf(v[k].x), fabsf(v[k].y)),
                                     fmaxf(fabsf(v[k].z), fabsf(v[k].w))));
    }
    float mm = 0.f;
    #pragma unroll
    for (int k = 0; k < 8; ++k) mm = fmaxf(mm, m[k]);
    for (int off = 32; off; off >>= 1)
        mm = fmaxf(mm, __shfl_down(mm, off));
    __shared__ float wm[4];
    const int lane = t & 63, wave = t >> 6;
    if (lane == 0) wm[wave] = mm;
    __syncthreads();
    if (t == 0)
        partial[blockIdx.x] = fmaxf(fmaxf(wm[0], wm[1]), fmaxf(wm[2], wm[3]));
}

// ---------- Kernel 2 (fused): w group-sums + x quantize/group-sum ----------
// Saves one launch gap (~10 us; r1 accounting shows >=40 us of inter-dispatch
// gaps in dur_us). blocks [0,2048): wsum; blocks [2048,6144): xquant.
// xquant blocks re-reduce the 2048 partials in-block (deterministic, L2-hit).
// No clamps: |v|*127/bm <= 127*(1+eps) < 127.5, rint exact.
__global__ void prep2(const float* __restrict__ w,
                      const float* __restrict__ x,
                      const float* __restrict__ partial,
                      const float* __restrict__ wscale,
                      float* __restrict__ sc,
                      _Float16* __restrict__ ws,
                      _Float16* __restrict__ xs) {
    const int t = threadIdx.x;
    const int b = blockIdx.x;
    if (b < 2048) {
        // w group-sums: lane owns 8 consecutive groups -> 8x16B loads + 16B store.
        const long g0 = (long)b * 2048 + (long)t * 8;
        f32x4 v[8];
        #pragma unroll
        for (int j = 0; j < 8; ++j)
            v[j] = *(const f32x4*)(w + (g0 + j) * 4);
        f16x8 r;
        #pragma unroll
        for (int j = 0; j < 8; ++j)
            r[j] = (_Float16)(v[j][0] + v[j][1] + v[j][2] + v[j][3]);  // int in [-4,4]: exact
        *(f16x8*)(ws + g0) = r;
    } else {
        float m = 0.f;
        #pragma unroll
        for (int u = 0; u < 8; ++u)
            m = fmaxf(m, partial[t + u * 256]);
        for (int off = 32; off; off >>= 1)
            m = fmaxf(m, __shfl_down(m, off));
        __shared__ float wm[4];
        const int lane = t & 63, wave = t >> 6;
        if (lane == 0) wm[wave] = m;
        __syncthreads();
        const float bm = fmaxf(fmaxf(wm[0], wm[1]), fmaxf(wm[2], wm[3]));
        const float inv = 127.0f / bm;
        if (b == 2048 && t == 0) {
            float s = bm * (1.0f / 127.0f);
            sc[0] = s;                       // act_scale
            sc[2] = s * 0.25f * wscale[0];   // fused epilogue scale for GEMM
        }
        const long g0 = (long)(b - 2048) * 2048 + (long)t * 8;
        f32x4 v[8];
        #pragma unroll
        for (int j = 0; j < 8; ++j)
            v[j] = *(const f32x4*)(x + (g0 + j) * 4);
        f16x8 r;
        #pragma unroll
        for (int j = 0; j < 8; ++j)
            r[j] = (_Float16)(rintf(v[j][0] * inv) + rintf(v[j][1] * inv) +
                              rintf(v[j][2] * inv) + rintf(v[j][3] * inv));
        *(f16x8*)(xs + g0) = r;
    }
}

// ---------- Kernel 3: f16 MFMA GEMM, 256x128 tile, 8 waves, 64x64 wave tile ----------
// Change vs r6 (111.5 us, MfmaUtil 24%): 512 threads/block, wave tile 64x64
// (acc 4x4), 2 blocks/CU -> 16 waves/CU (was 8). Halves each wave's serial
// ds_read->MFMA chain; waves hide each other's lgkm/vm stalls (m114 mechanism).
// Plus NT stores (clean A/B vs r6: does the 134 MB out-stream thrash L3?).
#define BM 256
#define BN 128
#define BK 32

__device__ __forceinline__ void async_copy16(const void* g, void* l) {
    __builtin_amdgcn_global_load_lds(
        (const __attribute__((address_space(1))) unsigned int*)g,
        (__attribute__((address_space(3))) unsigned int*)l,
        16, 0, 0);
}

__global__ __launch_bounds__(512, 4) void gemm_kernel(
    const _Float16* __restrict__ A,
    const _Float16* __restrict__ B,
    const float* __restrict__ bias,
    const float* __restrict__ sc,
    float* __restrict__ out) {

    // Double-buffered: 2 x (16 KB A + 8 KB B) = 48 KB -> 2 blocks/CU (96 KB).
    __shared__ alignas(16) _Float16 As[2][BM * BK];
    __shared__ alignas(16) _Float16 Bs[2][BN * BK];

    const int t = threadIdx.x;
    const int lane = t & 63;
    const int wave = t >> 6;            // 0..7
    const int wm = (wave >> 1) * 64;    // 4 wave-rows (M)
    const int wn = (wave & 1) * 64;     // 2 wave-cols (N)

    const long rowA0 = (long)blockIdx.y * BM;
    const long rowB0 = (long)blockIdx.x * BN;

    f32x4 acc[4][4] = {};

    // Staging: chunk = 1 KB = 16 rows x 32 f16. LDS dest linear (global_load_lds
    // writes base + lane*16); bank-conflict swizzle applied on the GLOBAL source
    // column (both-sides rule): phys_col8 = col8 ^ ((row>>1)&3)<<3.
    const int srow = lane >> 2;
    const int scol = ((lane & 3) << 3) ^ (((lane >> 3) & 3) << 3);
    const int swzR = ((lane >> 1) & 3) << 3;

    auto stage = [&](int buf, int k0) {
        #pragma unroll
        for (int i = 0; i < 3; ++i) {
            const int c = wave * 3 + i;       // wave-uniform chunk id, 24 = 16 A + 8 B
            if (c < 16) {
                const int row = c * 16 + srow;
                async_copy16(A + (rowA0 + row) * (long)G + k0 + scol, &As[buf][c * 512]);
            } else {
                const int row = (c - 16) * 16 + srow;
                async_copy16(B + (rowB0 + row) * (long)G + k0 + scol, &Bs[buf][(c - 16) * 512]);
            }
        }
    };

    stage(0, 0);
    __syncthreads();   // compiler drains vmcnt(0) before s_barrier

    int cur = 0;
    for (int ks = 0; ks < G / BK; ++ks) {
        if (ks + 1 < G / BK) stage(cur ^ 1, (ks + 1) * BK);

        f16x8 af[4], bf[4];
        #pragma unroll
        for (int mi = 0; mi < 4; ++mi)
            af[mi] = *(const f16x8*)&As[cur][(wm + mi * 16 + (lane & 15)) * BK
                                            + (((lane >> 4) * 8) ^ swzR)];
        #pragma unroll
        for (int nj = 0; nj < 4; ++nj)
            bf[nj] = *(const f16x8*)&Bs[cur][(wn + nj * 16 + (lane & 15)) * BK
                                            + (((lane >> 4) * 8) ^ swzR)];

        #pragma unroll
        for (int mi = 0; mi < 4; ++mi)
            #pragma unroll
            for (int nj = 0; nj < 4; ++nj)
                acc[mi][nj] = __builtin_amdgcn_mfma_f32_16x16x32_f16(
                    af[mi], bf[nj], acc[mi][nj], 0, 0, 0);

        __syncthreads();  // reads of buf[cur] done + stages into buf[cur^1] drained
        cur ^= 1;
    }

    // epilogue: D[m=(lane>>4)*4+r][n=lane&15] per 16x16 tile. NT stores: out
    // (134 MB) is never re-read; keep A/B panels resident in L2/L3.
    const float scale = sc[2];
    const int r0 = (int)rowA0 + wm + (lane >> 4) * 4;
    const int c0 = (int)rowB0 + wn + (lane & 15);
    #pragma unroll
    for (int nj = 0; nj < 4; ++nj) {
        const int col = c0 + nj * 16;
        const float b = bias[col];
        #pragma unroll
        for (int mi = 0; mi < 4; ++mi) {
            const int row = r0 + mi * 16;
            #pragma unroll
            for (int r = 0; r < 4; ++r)
                __builtin_nontemporal_store(acc[mi][nj][r] * scale + b,
                                            &out[(long)(row + r) * OUTF + col]);
        }
    }
}

extern "C" void kernel_launch(void* const* d_in, const int* in_sizes, int n_in,
                              void* d_out, int out_size, void* d_ws, size_t ws_size,
                              hipStream_t stream) {
    const float* input  = (const float*)d_in[0];   // [8192][4096]
    const float* weight = (const float*)d_in[1];   // [4096][4096]
    const float* wscale = (const float*)d_in[2];   // [1]
    const float* bias   = (const float*)d_in[3];   // [4096]
    float* out = (float*)d_out;

    float* scales   = (float*)d_ws;
    float* partials = (float*)((char*)d_ws + 16);
    _Float16* x_sum = (_Float16*)((char*)d_ws + 8208);
    _Float16* w_sum = (_Float16*)((char*)d_ws + 8208 + (size_t)NROWS * G * 2);

    absmax_part<<<2048, 256, 0, stream>>>((const float4*)input, partials);
    prep2<<<6144, 256, 0, stream>>>(weight, input, partials, wscale,
                                    scales, w_sum, x_sum);
    gemm_kernel<<<dim3(OUTF / BN, NROWS / BM), 512, 0, stream>>>(
        x_sum, w_sum, bias, scales, out);
}